// Round 13
// baseline (93.810 us; speedup 1.0000x reference)
//
#include <hip/hip_runtime.h>
#include <hip/hip_bf16.h>

#define NB 8
#define NT 2048
#define NE 1024
#define NH 64

typedef __bf16 bf16_t;
typedef __bf16 bf16x8 __attribute__((ext_vector_type(8)));
typedef float f32x4 __attribute__((ext_vector_type(4)));

#define MFMA16(a, b, c) __builtin_amdgcn_mfma_f32_16x16x32_bf16(a, b, c, 0, 0, 0)

static __device__ __forceinline__ f32x4 fzero4() {
    f32x4 z = {0.f, 0.f, 0.f, 0.f};
    return z;
}

// async global -> LDS, 16 B per lane. LDS dest is wave-uniform base + lane*16
// (HW rule, m104/m108); global src is per-lane (pre-swizzle goes on the src).
static __device__ __forceinline__ void gload_lds16(const void* gsrc, void* ldst) {
    __builtin_amdgcn_global_load_lds(
        (const __attribute__((address_space(1))) char*)gsrc,
        (__attribute__((address_space(3))) char*)ldst, 16, 0, 0);
}

// NT (non-temporal, CPol bit1 = 2) variant for read-once streams: hints the
// cache hierarchy not to retain/allocate. R13 theory: the x-stream ceiling
// (~2.5 TB/s = 1 line/cy/XCD) is the L2 line-ALLOCATE rate on compulsory
// misses; NT routes the read-once x stream around allocation pressure.
static __device__ __forceinline__ void gload_lds16_nt(const void* gsrc, void* ldst) {
    __builtin_amdgcn_global_load_lds(
        (const __attribute__((address_space(1))) char*)gsrc,
        (__attribute__((address_space(3))) char*)ldst, 16, 0, 2);
}

// ---------------------------------------------------------------------------
// Kernel 0: convert W (f32) -> bf16 workspace. Wb layout: [0]=Wq, [1]=Wk, [2]=Wv
// ---------------------------------------------------------------------------
__global__ __launch_bounds__(256) void convw_kernel(
    const float* __restrict__ Wq, const float* __restrict__ Wk,
    const float* __restrict__ Wv, bf16_t* __restrict__ Wb)
{
    int src = blockIdx.y;
    const float* W = (src == 0) ? Wq : ((src == 1) ? Wk : Wv);
    int idx = (blockIdx.x * 256 + threadIdx.x) * 8;  // 32 blocks * 256 thr * 8 = 65536
    f32x4 a = *(const f32x4*)(W + idx);
    f32x4 b = *(const f32x4*)(W + idx + 4);
    bf16x8 o;
#pragma unroll
    for (int j = 0; j < 4; ++j) { o[j] = (bf16_t)a[j]; o[4 + j] = (bf16_t)b[j]; }
    *(bf16x8*)(Wb + (size_t)src * (NH * NE) + idx) = o;
}

// ---------------------------------------------------------------------------
// Kernel 1: projections, W-shared-via-LDS (R11 structure, best measured:
// proj ~76 us, total 85.2) + NT cache policy on the x stream (R13's single
// variable). R12's counted-vmcnt/4-buffer pipeline REGRESSED (86 us) and is
// reverted; barrier-count evidence (R7 BK64=83 vs R11 BK32=76) killed the
// drain theory.
// Empirical wall being tested: x-stream (read-once, L2-compulsory-miss)
// runs at 2.0-2.6 TB/s in EVERY structure tried = ~1 cacheline/cy/XCD =
// candidate L2 fill-rate limit. NT on x (aux=2) is the cache-policy probe.
// Structure: grid (256, 3) = 768 blocks = exactly 3/CU. Block = 64 t-rows,
// 4 waves x 16 rows. K-loop: 32 steps of BK=32, double-buffered:
//   per step per wave: 2 gload_lds_nt (own x rows, 2 KB) + 1 gload_lds (its
//   quarter of the shared W slice, 1 KB); one __syncthreads per step.
// LDS: x [2][4 waves][16r x 8ch x 16B] = 16 KB; W [2][4 kch][64 h][16B] = 8 KB.
// Swizzles (source-side, G21/m173): x chunk phys = logical ^ (row&7);
// W is chunk-major [kchunk][h] (bank-conflict counter shows conflicts are
// negligible: 786k cycles/dispatch = 0.3% -- not worth touching).
//   y=0: qh[t][h] = q . Wq   (A = x rows, B = W)
//   y=1: kh[t][h] = k . Wk
//   y=2: vhT[b][h][t] = v . Wv (A = W, B = x -> accumulator is [h][t])
// MFMA 16x16x32 conventions (m89/m91-verified):
//   A-frag: lane holds A[row=lane&15][k=(lane>>4)*8 + j]
//   B-frag: lane holds B[k=(lane>>4)*8 + j][col=lane&15]
//   D:      col = lane&15, row = (lane>>4)*4 + reg
// ---------------------------------------------------------------------------
__global__ __launch_bounds__(256) void proj_kernel(
    const float* __restrict__ q_in, const float* __restrict__ k_in,
    const float* __restrict__ v_in, const bf16_t* __restrict__ Wb,
    bf16_t* __restrict__ qh, bf16_t* __restrict__ kh, bf16_t* __restrict__ vhT)
{
    const int which = blockIdx.y;
    const int w    = threadIdx.x >> 6;   // wave 0..3: owns t-rows w*16..+16, stages W kchunk w
    const int lane = threadIdx.x & 63;
    const int l15  = lane & 15;
    const int lhi  = lane >> 4;
    const int t0   = blockIdx.x * 64;

    const float*  x = (which == 0) ? q_in : ((which == 1) ? k_in : v_in);
    const bf16_t* W = Wb + (size_t)which * (NH * NE);

    __shared__ __align__(16) char xlds[2][4][2048];  // [buf][wave][16 rows][8 ch][16B]
    __shared__ __align__(16) char wlds[2][4096];     // [buf][4 kchunk][64 h][16B]

    // ---- staging sources (per-lane, pre-swizzled; step adds k floats) ----
    // x instr i (i=0,1): rows i*8+(lane>>3) of this wave's 16; phys chunk lane&7
    const float* xsrc[2];
#pragma unroll
    for (int i = 0; i < 2; ++i) {
        int rw   = i * 8 + (lane >> 3);
        int phys = lane & 7;
        xsrc[i] = x + (size_t)(t0 + w * 16 + rw) * NE + ((phys ^ (rw & 7)) << 2);
    }
    // W instr: wave w stages kchunk w (k = w*8..w*8+7 of the 32-slice); lane = h
    const bf16_t* wsrc = W + (size_t)lane * NE + w * 8;

    // ---- fragment read byte-offsets (buffer-invariant) -------------------
    int xo[2];
#pragma unroll
    for (int j = 0; j < 2; ++j)
        xo[j] = l15 * 128 + ((((lhi * 2 + j) ^ (l15 & 7))) << 4);
    int wo[4];
#pragma unroll
    for (int cg = 0; cg < 4; ++cg)
        wo[cg] = lhi * 1024 + (cg * 16 + l15) * 16;

    f32x4 acc[4] = {fzero4(), fzero4(), fzero4(), fzero4()};

    // ---- prologue: stage step 0 into buf 0 -------------------------------
    gload_lds16_nt(xsrc[0], &xlds[0][w][0]);
    gload_lds16_nt(xsrc[1], &xlds[0][w][1024]);
    gload_lds16(wsrc, &wlds[0][w * 1024]);
    __syncthreads();

    // ---- K-loop: 32 steps of K=32, dbuf, one barrier/step ----------------
#pragma unroll 4
    for (int step = 0; step < 32; ++step) {
        const int cur = step & 1;
        if (step < 31) {
            const int k0 = (step + 1) * 32;
            gload_lds16_nt(xsrc[0] + k0, &xlds[cur ^ 1][w][0]);
            gload_lds16_nt(xsrc[1] + k0, &xlds[cur ^ 1][w][1024]);
            gload_lds16(wsrc + k0, &wlds[cur ^ 1][w * 1024]);
        }
        const char* xb = xlds[cur][w];
        const char* wb = wlds[cur];

        f32x4 a0 = *(const f32x4*)(xb + xo[0]);
        f32x4 a1 = *(const f32x4*)(xb + xo[1]);
        bf16x8 xf;
#pragma unroll
        for (int j = 0; j < 4; ++j) { xf[j] = (bf16_t)a0[j]; xf[4 + j] = (bf16_t)a1[j]; }

        if (which < 2) {
            acc[0] = MFMA16(xf, *(const bf16x8*)(wb + wo[0]), acc[0]);
            acc[1] = MFMA16(xf, *(const bf16x8*)(wb + wo[1]), acc[1]);
            acc[2] = MFMA16(xf, *(const bf16x8*)(wb + wo[2]), acc[2]);
            acc[3] = MFMA16(xf, *(const bf16x8*)(wb + wo[3]), acc[3]);
        } else {
            acc[0] = MFMA16(*(const bf16x8*)(wb + wo[0]), xf, acc[0]);
            acc[1] = MFMA16(*(const bf16x8*)(wb + wo[1]), xf, acc[1]);
            acc[2] = MFMA16(*(const bf16x8*)(wb + wo[2]), xf, acc[2]);
            acc[3] = MFMA16(*(const bf16x8*)(wb + wo[3]), xf, acc[3]);
        }
        __syncthreads();   // vmcnt drain at barrier: next buffer complete
    }

    // ---- epilogue ---------------------------------------------------------
    if (which < 2) {
        bf16_t* outp = (which == 0) ? qh : kh;
#pragma unroll
        for (int cg = 0; cg < 4; ++cg)
#pragma unroll
            for (int r = 0; r < 4; ++r) {
                int t = t0 + w * 16 + lhi * 4 + r;
                outp[(size_t)t * NH + cg * 16 + l15] = (bf16_t)acc[cg][r];
            }
    } else {
        // D (A=W): row = h within group (lhi*4+r), col = t within 16 (l15)
        const int tg = t0 + w * 16 + l15;
        const int b  = tg >> 11;
        const int tt = tg & 2047;
#pragma unroll
        for (int hg = 0; hg < 4; ++hg)
#pragma unroll
            for (int r = 0; r < 4; ++r) {
                int h = hg * 16 + lhi * 4 + r;
                vhT[(((size_t)(b * NH + h)) << 11) + tt] = (bf16_t)acc[hg][r];
            }
    }
}

// ---------------------------------------------------------------------------
// Kernel 2: split-K flash attention, causal + key-mask.
// grid = (B*T/16) linear blocks, 256 thr. Block owns ONE 16-row q-tile; its
// 4 waves split the causal key range 4 ways (64-key tiles each), then merge
// partial (m, l, O) through LDS.
// ---------------------------------------------------------------------------
__global__ __launch_bounds__(256) void attn_kernel(
    const bf16_t* __restrict__ qh, const bf16_t* __restrict__ kh,
    const bf16_t* __restrict__ vhT, const int* __restrict__ mask,
    float* __restrict__ out)
{
    const int lin  = blockIdx.x;
    const int qt16 = lin >> 3;     // 0..127: q-tile (16 rows)
    const int b    = lin & 7;
    const int w    = threadIdx.x >> 6;   // key-split index 0..3
    const int lane = threadIdx.x & 63;
    const int l15  = lane & 15;
    const int lhi  = lane >> 4;

    __shared__ __align__(16) char plds[4][2][2048];   // [wave][dbuf][16x64 bf16]
    __shared__ float sm_o[4][16][65];                  // [wave][row][col] (+1 pad)
    __shared__ float sm_ml[4][2][16];                  // [wave][m/l][row]

    const int q0  = qt16 * 16;
    const int nkt = (q0 + 15) / 64 + 1;     // causal 64-key tiles
    const int len = (nkt + 3) >> 2;         // ceil(nkt/4)
    const int kt_beg = w * len;
    const int kt_end = min(kt_beg + len, nkt);

    // Q fragments (H=64 -> two k-chunks of 32)
    const bf16_t* qbase = qh + (size_t)(b * NT + q0 + l15) * NH + lhi * 8;
    bf16x8 qf0 = *(const bf16x8*)(qbase);
    bf16x8 qf1 = *(const bf16x8*)(qbase + 32);

    f32x4 acc_o[4] = {fzero4(), fzero4(), fzero4(), fzero4()};
    float m[4]    = {-1e30f, -1e30f, -1e30f, -1e30f};
    float lsum[4] = {0.f, 0.f, 0.f, 0.f};

    const int qq0 = q0 + lhi * 4;  // this lane's first q-row

    for (int kt = kt_beg; kt < kt_end; ++kt) {
        // ---- S = (qh . kh^T) * 0.125, tile 16q x 64k --------------------
        const bf16_t* kbase = kh + (size_t)(b * NT + kt * 64 + l15) * NH + lhi * 8;
        f32x4 s[4] = {fzero4(), fzero4(), fzero4(), fzero4()};
#pragma unroll
        for (int cg = 0; cg < 4; ++cg) {
            bf16x8 kf0 = *(const bf16x8*)(kbase + (size_t)cg * 16 * NH);
            bf16x8 kf1 = *(const bf16x8*)(kbase + (size_t)cg * 16 * NH + 32);
            s[cg] = MFMA16(qf0, kf0, s[cg]);
            s[cg] = MFMA16(qf1, kf1, s[cg]);
        }

        // ---- mask + scale ----------------------------------------------
        int mk[4];
#pragma unroll
        for (int cg = 0; cg < 4; ++cg) mk[cg] = mask[b * NT + kt * 64 + cg * 16 + l15];
#pragma unroll
        for (int cg = 0; cg < 4; ++cg) {
            int kk = kt * 64 + cg * 16 + l15;
#pragma unroll
            for (int r = 0; r < 4; ++r) {
                float sv = s[cg][r] * 0.125f;
                bool ok = (kk <= qq0 + r) && (mk[cg] != 0);
                s[cg][r] = ok ? sv : -1e30f;
            }
        }

        // ---- online softmax (row spread over 16 lanes x 4 cgs) ----------
        float mx[4];
#pragma unroll
        for (int r = 0; r < 4; ++r) {
            mx[r] = fmaxf(fmaxf(s[0][r], s[1][r]), fmaxf(s[2][r], s[3][r]));
#pragma unroll
            for (int d = 1; d < 16; d <<= 1) mx[r] = fmaxf(mx[r], __shfl_xor(mx[r], d));
        }
        float resc[4];
#pragma unroll
        for (int r = 0; r < 4; ++r) {
            float mn = fmaxf(m[r], mx[r]);
            resc[r] = __expf(m[r] - mn);
            m[r] = mn;
        }
        float rs[4] = {0.f, 0.f, 0.f, 0.f};
#pragma unroll
        for (int cg = 0; cg < 4; ++cg)
#pragma unroll
            for (int r = 0; r < 4; ++r) {
                float sv = s[cg][r];
                float p = (sv > -5e29f) ? __expf(sv - m[r]) : 0.f;  // masked -> exactly 0
                s[cg][r] = p;
                rs[r] += p;
            }
#pragma unroll
        for (int r = 0; r < 4; ++r) {
#pragma unroll
            for (int d = 1; d < 16; d <<= 1) rs[r] += __shfl_xor(rs[r], d);
            lsum[r] = lsum[r] * resc[r] + rs[r];
        }
#pragma unroll
        for (int cg = 0; cg < 4; ++cg)
#pragma unroll
            for (int r = 0; r < 4; ++r) acc_o[cg][r] *= resc[r];

        // ---- P -> LDS (bf16, XOR swizzle: byte ^= (row&7)<<4) -----------
        char* pb = &plds[w][kt & 1][0];
#pragma unroll
        for (int cg = 0; cg < 4; ++cg)
#pragma unroll
            for (int r = 0; r < 4; ++r) {
                int row = lhi * 4 + r;
                int col = cg * 16 + l15;
                int byte = (row * 128 + col * 2) ^ ((row & 7) << 4);
                *(bf16_t*)(pb + byte) = (bf16_t)s[cg][r];
            }

        // ---- O += P . V  (A-frags from LDS, B-frags from vhT, contiguous)
        const bf16_t* vbase = vhT + ((size_t)(b * NH + l15) << 11) + kt * 64 + lhi * 8;
#pragma unroll
        for (int kc = 0; kc < 2; ++kc) {
            int row = l15;
            int byte = (row * 128 + kc * 64 + lhi * 16) ^ ((row & 7) << 4);
            bf16x8 pf = *(bf16x8*)(pb + byte);
#pragma unroll
            for (int cg = 0; cg < 4; ++cg) {
                bf16x8 vf = *(const bf16x8*)(vbase + ((size_t)cg * 16 << 11) + kc * 32);
                acc_o[cg] = MFMA16(pf, vf, acc_o[cg]);
            }
        }
    }

    // ---- write this wave's partials to LDS ------------------------------
#pragma unroll
    for (int cg = 0; cg < 4; ++cg)
#pragma unroll
        for (int r = 0; r < 4; ++r)
            sm_o[w][lhi * 4 + r][cg * 16 + l15] = acc_o[cg][r];
    if (l15 == 0) {
#pragma unroll
        for (int r = 0; r < 4; ++r) {
            sm_ml[w][0][lhi * 4 + r] = m[r];
            sm_ml[w][1][lhi * 4 + r] = lsum[r];
        }
    }
    __syncthreads();

    // ---- merge 4 splits; this thread covers col = w*16+l15, rows lhi*4+r
#pragma unroll
    for (int r = 0; r < 4; ++r) {
        int row = lhi * 4 + r;
        float mg = -1e30f;
#pragma unroll
        for (int s = 0; s < 4; ++s) mg = fmaxf(mg, sm_ml[s][0][row]);
        float lg = 0.f, og = 0.f;
#pragma unroll
        for (int s = 0; s < 4; ++s) {
            float e = __expf(sm_ml[s][0][row] - mg);
            lg += e * sm_ml[s][1][row];
            og += e * sm_o[s][row][w * 16 + l15];
        }
        out[(size_t)(b * NT + q0 + row) * NH + w * 16 + l15] = og / lg;
    }
}

// ---------------------------------------------------------------------------
extern "C" void kernel_launch(void* const* d_in, const int* in_sizes, int n_in,
                              void* d_out, int out_size, void* d_ws, size_t ws_size,
                              hipStream_t stream)
{
    const float* k_in = (const float*)d_in[0];
    const float* q_in = (const float*)d_in[1];
    const float* v_in = (const float*)d_in[2];
    const int*   mask = (const int*)d_in[3];
    const float* Wk   = (const float*)d_in[4];
    const float* Wq   = (const float*)d_in[5];
    const float* Wv   = (const float*)d_in[6];
    float* out = (float*)d_out;

    char* ws = (char*)d_ws;
    bf16_t* Wb  = (bf16_t*)ws;                       // 3*64*1024 bf16 = 384 KB
    bf16_t* qh  = (bf16_t*)(ws + 3 * NH * NE * 2);   // 16384*64 bf16 = 2 MB
    bf16_t* kh  = qh + (size_t)NB * NT * NH;
    bf16_t* vhT = kh + (size_t)NB * NT * NH;         // [8][64][2048] bf16 = 2 MB

    convw_kernel<<<dim3(32, 3), 256, 0, stream>>>(Wq, Wk, Wv, Wb);
    proj_kernel<<<dim3(NB * NT / 64, 3), 256, 0, stream>>>(q_in, k_in, v_in, Wb, qh, kh, vhT);
    attn_kernel<<<dim3(NB * NT / 16), 256, 0, stream>>>(qh, kh, vhT, mask, out);
}

// Round 15
// 85.178 us; speedup vs baseline: 1.1013x; 1.1013x over previous
//
#include <hip/hip_runtime.h>
#include <hip/hip_bf16.h>

#define NB 8
#define NT 2048
#define NE 1024
#define NH 64

typedef __bf16 bf16_t;
typedef __bf16 bf16x8 __attribute__((ext_vector_type(8)));
typedef float f32x4 __attribute__((ext_vector_type(4)));

#define MFMA16(a, b, c) __builtin_amdgcn_mfma_f32_16x16x32_bf16(a, b, c, 0, 0, 0)

static __device__ __forceinline__ f32x4 fzero4() {
    f32x4 z = {0.f, 0.f, 0.f, 0.f};
    return z;
}

// async global -> LDS, 16 B per lane. LDS dest is wave-uniform base + lane*16
// (HW rule, m104/m108); global src is per-lane (pre-swizzle goes on the src).
static __device__ __forceinline__ void gload_lds16(const void* gsrc, void* ldst) {
    __builtin_amdgcn_global_load_lds(
        (const __attribute__((address_space(1))) char*)gsrc,
        (__attribute__((address_space(3))) char*)ldst, 16, 0, 0);
}

// ---------------------------------------------------------------------------
// Kernel 0: convert W (f32) -> bf16 workspace. Wb layout: [0]=Wq, [1]=Wk, [2]=Wv
// ---------------------------------------------------------------------------
__global__ __launch_bounds__(256) void convw_kernel(
    const float* __restrict__ Wq, const float* __restrict__ Wk,
    const float* __restrict__ Wv, bf16_t* __restrict__ Wb)
{
    int src = blockIdx.y;
    const float* W = (src == 0) ? Wq : ((src == 1) ? Wk : Wv);
    int idx = (blockIdx.x * 256 + threadIdx.x) * 8;  // 32 blocks * 256 thr * 8 = 65536
    f32x4 a = *(const f32x4*)(W + idx);
    f32x4 b = *(const f32x4*)(W + idx + 4);
    bf16x8 o;
#pragma unroll
    for (int j = 0; j < 4; ++j) { o[j] = (bf16_t)a[j]; o[4 + j] = (bf16_t)b[j]; }
    *(bf16x8*)(Wb + (size_t)src * (NH * NE) + idx) = o;
}

// ---------------------------------------------------------------------------
// Kernel 1: projections, W-shared-via-LDS — EXACT R11 structure (the best
// verified configuration: total 85.2 us, replay-stable). R12 counted-vmcnt,
// R13 NT-policy, and R14's attn KVBLK=128 all regressed or raced and are
// reverted. proj moves 296 MB at ~5.4 TB/s effective, within ~15% of the
// measured per-CU port ceiling (10.3 B/cy/CU, m13); five structural
// alternatives measured null -> treated as proj's practical floor.
// Structure: grid (256, 3) = 768 blocks = 3/CU. Block = 64 t-rows, 4 waves
// x 16 rows. 32 steps of BK=32, double-buffered; per step per wave:
// 2 gload_lds (own x rows) + 1 gload_lds (quarter of shared W slice);
// one __syncthreads per step (barrier's vmcnt drain = next buffer ready).
//   y=0: qh[t][h] = q . Wq   (A = x rows, B = W)
//   y=1: kh[t][h] = k . Wk
//   y=2: vhT[b][h][t] = v . Wv (A = W, B = x -> accumulator is [h][t])
// MFMA 16x16x32 conventions (m89/m91-verified):
//   A-frag: lane holds A[row=lane&15][k=(lane>>4)*8 + j]
//   B-frag: lane holds B[k=(lane>>4)*8 + j][col=lane&15]
//   D:      col = lane&15, row = (lane>>4)*4 + reg
// ---------------------------------------------------------------------------
__global__ __launch_bounds__(256) void proj_kernel(
    const float* __restrict__ q_in, const float* __restrict__ k_in,
    const float* __restrict__ v_in, const bf16_t* __restrict__ Wb,
    bf16_t* __restrict__ qh, bf16_t* __restrict__ kh, bf16_t* __restrict__ vhT)
{
    const int which = blockIdx.y;
    const int w    = threadIdx.x >> 6;   // wave 0..3: owns t-rows w*16..+16, stages W kchunk w
    const int lane = threadIdx.x & 63;
    const int l15  = lane & 15;
    const int lhi  = lane >> 4;
    const int t0   = blockIdx.x * 64;

    const float*  x = (which == 0) ? q_in : ((which == 1) ? k_in : v_in);
    const bf16_t* W = Wb + (size_t)which * (NH * NE);

    __shared__ __align__(16) char xlds[2][4][2048];  // [buf][wave][16 rows][8 ch][16B]
    __shared__ __align__(16) char wlds[2][4096];     // [buf][4 kchunk][64 h][16B]

    // ---- staging sources (per-lane, pre-swizzled; step adds k floats) ----
    const float* xsrc[2];
#pragma unroll
    for (int i = 0; i < 2; ++i) {
        int rw   = i * 8 + (lane >> 3);
        int phys = lane & 7;
        xsrc[i] = x + (size_t)(t0 + w * 16 + rw) * NE + ((phys ^ (rw & 7)) << 2);
    }
    const bf16_t* wsrc = W + (size_t)lane * NE + w * 8;

    // ---- fragment read byte-offsets (buffer-invariant) -------------------
    int xo[2];
#pragma unroll
    for (int j = 0; j < 2; ++j)
        xo[j] = l15 * 128 + ((((lhi * 2 + j) ^ (l15 & 7))) << 4);
    int wo[4];
#pragma unroll
    for (int cg = 0; cg < 4; ++cg)
        wo[cg] = lhi * 1024 + (cg * 16 + l15) * 16;

    f32x4 acc[4] = {fzero4(), fzero4(), fzero4(), fzero4()};

    // ---- prologue: stage step 0 into buf 0 -------------------------------
    gload_lds16(xsrc[0], &xlds[0][w][0]);
    gload_lds16(xsrc[1], &xlds[0][w][1024]);
    gload_lds16(wsrc, &wlds[0][w * 1024]);
    __syncthreads();

    // ---- K-loop: 32 steps of K=32, dbuf, one barrier/step ----------------
#pragma unroll 4
    for (int step = 0; step < 32; ++step) {
        const int cur = step & 1;
        if (step < 31) {
            const int k0 = (step + 1) * 32;
            gload_lds16(xsrc[0] + k0, &xlds[cur ^ 1][w][0]);
            gload_lds16(xsrc[1] + k0, &xlds[cur ^ 1][w][1024]);
            gload_lds16(wsrc + k0, &wlds[cur ^ 1][w * 1024]);
        }
        const char* xb = xlds[cur][w];
        const char* wb = wlds[cur];

        f32x4 a0 = *(const f32x4*)(xb + xo[0]);
        f32x4 a1 = *(const f32x4*)(xb + xo[1]);
        bf16x8 xf;
#pragma unroll
        for (int j = 0; j < 4; ++j) { xf[j] = (bf16_t)a0[j]; xf[4 + j] = (bf16_t)a1[j]; }

        if (which < 2) {
            acc[0] = MFMA16(xf, *(const bf16x8*)(wb + wo[0]), acc[0]);
            acc[1] = MFMA16(xf, *(const bf16x8*)(wb + wo[1]), acc[1]);
            acc[2] = MFMA16(xf, *(const bf16x8*)(wb + wo[2]), acc[2]);
            acc[3] = MFMA16(xf, *(const bf16x8*)(wb + wo[3]), acc[3]);
        } else {
            acc[0] = MFMA16(*(const bf16x8*)(wb + wo[0]), xf, acc[0]);
            acc[1] = MFMA16(*(const bf16x8*)(wb + wo[1]), xf, acc[1]);
            acc[2] = MFMA16(*(const bf16x8*)(wb + wo[2]), xf, acc[2]);
            acc[3] = MFMA16(*(const bf16x8*)(wb + wo[3]), xf, acc[3]);
        }
        __syncthreads();   // vmcnt drain at barrier: next buffer complete
    }

    // ---- epilogue ---------------------------------------------------------
    if (which < 2) {
        bf16_t* outp = (which == 0) ? qh : kh;
#pragma unroll
        for (int cg = 0; cg < 4; ++cg)
#pragma unroll
            for (int r = 0; r < 4; ++r) {
                int t = t0 + w * 16 + lhi * 4 + r;
                outp[(size_t)t * NH + cg * 16 + l15] = (bf16_t)acc[cg][r];
            }
    } else {
        const int tg = t0 + w * 16 + l15;
        const int b  = tg >> 11;
        const int tt = tg & 2047;
#pragma unroll
        for (int hg = 0; hg < 4; ++hg)
#pragma unroll
            for (int r = 0; r < 4; ++r) {
                int h = hg * 16 + lhi * 4 + r;
                vhT[(((size_t)(b * NH + h)) << 11) + tt] = (bf16_t)acc[hg][r];
            }
    }
}

// ---------------------------------------------------------------------------
// Kernel 2: split-K flash attention, causal + key-mask — EXACT R11 version
// (64-key rounds; replay-stable across R11/R13's post-timing checks).
// R14's KVBLK=128 variant diverged under replay (suspected LDS race) and
// was perf-neutral (causal masking wasted the wider tile) -> reverted.
// grid = (B*T/16) linear blocks, 256 thr. Block owns ONE 16-row q-tile; its
// 4 waves split the causal key range 4 ways (64-key tiles each), then merge
// partial (m, l, O) through LDS.
// ---------------------------------------------------------------------------
__global__ __launch_bounds__(256) void attn_kernel(
    const bf16_t* __restrict__ qh, const bf16_t* __restrict__ kh,
    const bf16_t* __restrict__ vhT, const int* __restrict__ mask,
    float* __restrict__ out)
{
    const int lin  = blockIdx.x;
    const int qt16 = lin >> 3;     // 0..127: q-tile (16 rows)
    const int b    = lin & 7;
    const int w    = threadIdx.x >> 6;   // key-split index 0..3
    const int lane = threadIdx.x & 63;
    const int l15  = lane & 15;
    const int lhi  = lane >> 4;

    __shared__ __align__(16) char plds[4][2][2048];   // [wave][dbuf][16x64 bf16]
    __shared__ float sm_o[4][16][65];                  // [wave][row][col] (+1 pad)
    __shared__ float sm_ml[4][2][16];                  // [wave][m/l][row]

    const int q0  = qt16 * 16;
    const int nkt = (q0 + 15) / 64 + 1;     // causal 64-key tiles
    const int len = (nkt + 3) >> 2;         // ceil(nkt/4)
    const int kt_beg = w * len;
    const int kt_end = min(kt_beg + len, nkt);

    // Q fragments (H=64 -> two k-chunks of 32)
    const bf16_t* qbase = qh + (size_t)(b * NT + q0 + l15) * NH + lhi * 8;
    bf16x8 qf0 = *(const bf16x8*)(qbase);
    bf16x8 qf1 = *(const bf16x8*)(qbase + 32);

    f32x4 acc_o[4] = {fzero4(), fzero4(), fzero4(), fzero4()};
    float m[4]    = {-1e30f, -1e30f, -1e30f, -1e30f};
    float lsum[4] = {0.f, 0.f, 0.f, 0.f};

    const int qq0 = q0 + lhi * 4;  // this lane's first q-row

    for (int kt = kt_beg; kt < kt_end; ++kt) {
        // ---- S = (qh . kh^T) * 0.125, tile 16q x 64k --------------------
        const bf16_t* kbase = kh + (size_t)(b * NT + kt * 64 + l15) * NH + lhi * 8;
        f32x4 s[4] = {fzero4(), fzero4(), fzero4(), fzero4()};
#pragma unroll
        for (int cg = 0; cg < 4; ++cg) {
            bf16x8 kf0 = *(const bf16x8*)(kbase + (size_t)cg * 16 * NH);
            bf16x8 kf1 = *(const bf16x8*)(kbase + (size_t)cg * 16 * NH + 32);
            s[cg] = MFMA16(qf0, kf0, s[cg]);
            s[cg] = MFMA16(qf1, kf1, s[cg]);
        }

        // ---- mask + scale ----------------------------------------------
        int mk[4];
#pragma unroll
        for (int cg = 0; cg < 4; ++cg) mk[cg] = mask[b * NT + kt * 64 + cg * 16 + l15];
#pragma unroll
        for (int cg = 0; cg < 4; ++cg) {
            int kk = kt * 64 + cg * 16 + l15;
#pragma unroll
            for (int r = 0; r < 4; ++r) {
                float sv = s[cg][r] * 0.125f;
                bool ok = (kk <= qq0 + r) && (mk[cg] != 0);
                s[cg][r] = ok ? sv : -1e30f;
            }
        }

        // ---- online softmax (row spread over 16 lanes x 4 cgs) ----------
        float mx[4];
#pragma unroll
        for (int r = 0; r < 4; ++r) {
            mx[r] = fmaxf(fmaxf(s[0][r], s[1][r]), fmaxf(s[2][r], s[3][r]));
#pragma unroll
            for (int d = 1; d < 16; d <<= 1) mx[r] = fmaxf(mx[r], __shfl_xor(mx[r], d));
        }
        float resc[4];
#pragma unroll
        for (int r = 0; r < 4; ++r) {
            float mn = fmaxf(m[r], mx[r]);
            resc[r] = __expf(m[r] - mn);
            m[r] = mn;
        }
        float rs[4] = {0.f, 0.f, 0.f, 0.f};
#pragma unroll
        for (int cg = 0; cg < 4; ++cg)
#pragma unroll
            for (int r = 0; r < 4; ++r) {
                float sv = s[cg][r];
                float p = (sv > -5e29f) ? __expf(sv - m[r]) : 0.f;  // masked -> exactly 0
                s[cg][r] = p;
                rs[r] += p;
            }
#pragma unroll
        for (int r = 0; r < 4; ++r) {
#pragma unroll
            for (int d = 1; d < 16; d <<= 1) rs[r] += __shfl_xor(rs[r], d);
            lsum[r] = lsum[r] * resc[r] + rs[r];
        }
#pragma unroll
        for (int cg = 0; cg < 4; ++cg)
#pragma unroll
            for (int r = 0; r < 4; ++r) acc_o[cg][r] *= resc[r];

        // ---- P -> LDS (bf16, XOR swizzle: byte ^= (row&7)<<4) -----------
        char* pb = &plds[w][kt & 1][0];
#pragma unroll
        for (int cg = 0; cg < 4; ++cg)
#pragma unroll
            for (int r = 0; r < 4; ++r) {
                int row = lhi * 4 + r;
                int col = cg * 16 + l15;
                int byte = (row * 128 + col * 2) ^ ((row & 7) << 4);
                *(bf16_t*)(pb + byte) = (bf16_t)s[cg][r];
            }

        // ---- O += P . V  (A-frags from LDS, B-frags from vhT, contiguous)
        const bf16_t* vbase = vhT + ((size_t)(b * NH + l15) << 11) + kt * 64 + lhi * 8;
#pragma unroll
        for (int kc = 0; kc < 2; ++kc) {
            int row = l15;
            int byte = (row * 128 + kc * 64 + lhi * 16) ^ ((row & 7) << 4);
            bf16x8 pf = *(bf16x8*)(pb + byte);
#pragma unroll
            for (int cg = 0; cg < 4; ++cg) {
                bf16x8 vf = *(const bf16x8*)(vbase + ((size_t)cg * 16 << 11) + kc * 32);
                acc_o[cg] = MFMA16(pf, vf, acc_o[cg]);
            }
        }
    }

    // ---- write this wave's partials to LDS ------------------------------
#pragma unroll
    for (int cg = 0; cg < 4; ++cg)
#pragma unroll
        for (int r = 0; r < 4; ++r)
            sm_o[w][lhi * 4 + r][cg * 16 + l15] = acc_o[cg][r];
    if (l15 == 0) {
#pragma unroll
        for (int r = 0; r < 4; ++r) {
            sm_ml[w][0][lhi * 4 + r] = m[r];
            sm_ml[w][1][lhi * 4 + r] = lsum[r];
        }
    }
    __syncthreads();

    // ---- merge 4 splits; this thread covers col = w*16+l15, rows lhi*4+r
#pragma unroll
    for (int r = 0; r < 4; ++r) {
        int row = lhi * 4 + r;
        float mg = -1e30f;
#pragma unroll
        for (int s = 0; s < 4; ++s) mg = fmaxf(mg, sm_ml[s][0][row]);
        float lg = 0.f, og = 0.f;
#pragma unroll
        for (int s = 0; s < 4; ++s) {
            float e = __expf(sm_ml[s][0][row] - mg);
            lg += e * sm_ml[s][1][row];
            og += e * sm_o[s][row][w * 16 + l15];
        }
        out[(size_t)(b * NT + q0 + row) * NH + w * 16 + l15] = og / lg;
    }
}

// ---------------------------------------------------------------------------
extern "C" void kernel_launch(void* const* d_in, const int* in_sizes, int n_in,
                              void* d_out, int out_size, void* d_ws, size_t ws_size,
                              hipStream_t stream)
{
    const float* k_in = (const float*)d_in[0];
    const float* q_in = (const float*)d_in[1];
    const float* v_in = (const float*)d_in[2];
    const int*   mask = (const int*)d_in[3];
    const float* Wk   = (const float*)d_in[4];
    const float* Wq   = (const float*)d_in[5];
    const float* Wv   = (const float*)d_in[6];
    float* out = (float*)d_out;

    char* ws = (char*)d_ws;
    bf16_t* Wb  = (bf16_t*)ws;                       // 3*64*1024 bf16 = 384 KB
    bf16_t* qh  = (bf16_t*)(ws + 3 * NH * NE * 2);   // 16384*64 bf16 = 2 MB
    bf16_t* kh  = qh + (size_t)NB * NT * NH;
    bf16_t* vhT = kh + (size_t)NB * NT * NH;         // [8][64][2048] bf16 = 2 MB

    convw_kernel<<<dim3(32, 3), 256, 0, stream>>>(Wq, Wk, Wv, Wb);
    proj_kernel<<<dim3(NB * NT / 64, 3), 256, 0, stream>>>(q_in, k_in, v_in, Wb, qh, kh, vhT);
    attn_kernel<<<dim3(NB * NT / 16), 256, 0, stream>>>(qh, kh, vhT, mask, out);
}